// Round 12
// baseline (433.615 us; speedup 1.0000x reference)
//
#include <hip/hip_runtime.h>
#include <math.h>

#define T 8192
#define M 4096          // half length (complex FFT size)
#define JS 4104         // padded row stride (elements) for half-spectra
#define B 8
#define CIN 32
#define COUT 32
#define HID 64
#define NB 256
#define NT 512

__device__ inline float2 cadd(float2 a, float2 b){ return make_float2(a.x+b.x, a.y+b.y); }
__device__ inline float2 csub(float2 a, float2 b){ return make_float2(a.x-b.x, a.y-b.y); }
__device__ inline float2 cmul(float2 a, float2 b){ return make_float2(a.x*b.x - a.y*b.y, a.x*b.y + a.y*b.x); }
__device__ inline float2 cmulc(float2 a, float2 b){ // a * conj(b)
    return make_float2(a.x*b.x + a.y*b.y, a.y*b.x - a.x*b.y); }
__device__ inline float2 rot90(float2 a){ return make_float2(a.y, -a.x); }   // * (0,-1)
__device__ inline int swz(int p){ return p ^ ((p >> 5) & 31); }
__device__ inline int brev12(int v){ return (int)(__brev((unsigned)v) >> 20); }

// e^{-2*pi*i * k/8192} on the fly (hw v_sin/v_cos; ~2e-7 error)
__device__ inline float2 cis_m(float k){
    const float w = -7.669903939428206e-4f;    // -2*pi/8192
    float a = w * k;
    return make_float2(__cosf(a), __sinf(a));
}

__device__ inline float gelu_exact(float x){
    return 0.5f*x*(1.0f + erff(x*0.70710678118654752440f));
}

// Monotone-counter grid barrier (counter zeroed by hipMemsetAsync before launch).
__device__ inline void grid_sync(unsigned* bar){
    __syncthreads();
    __threadfence();
    if (threadIdx.x == 0){
        unsigned my = atomicAdd(bar, 1u);              // device-scope [m20]
        unsigned target = (my/NB + 1u)*NB;
        while (__hip_atomic_load(bar, __ATOMIC_RELAXED, __HIP_MEMORY_SCOPE_AGENT) < target){
            __builtin_amdgcn_s_sleep(8);
        }
    }
    __syncthreads();
    __threadfence();
}

// ---- register-blocked radix-2 groups, 8 pts/thread, on-the-fly twiddles.
// S<<SH0 == 1024 in every instantiation -> stage deltas are -1/8 and -1/4 turns.
template<int SH0>
__device__ inline void dif_group8_o(float2 q[8], int r){
    const float c8 = 0.70710678118654752440f;
    const float2 R8 = make_float2(c8, -c8);
    float2 b0 = cis_m((float)(r << SH0));
    float2 w0[4];
    w0[0] = b0; w0[1] = cmul(b0, R8); w0[2] = rot90(b0); w0[3] = rot90(w0[1]);
    #pragma unroll
    for (int k = 0; k < 4; ++k){
        const int lo = k, hi = k + 4;
        float2 a = q[lo], b = q[hi];
        q[lo] = cadd(a, b);
        q[hi] = cmul(csub(a, b), w0[k]);
    }
    float2 b1 = cmul(b0, b0);
    float2 w1r = rot90(b1);
    #pragma unroll
    for (int k = 0; k < 4; ++k){
        const int jd = k & 1;
        const int lo = ((k & ~1) << 1) | jd, hi = lo + 2;
        float2 a = q[lo], b = q[hi];
        q[lo] = cadd(a, b);
        q[hi] = cmul(csub(a, b), jd ? w1r : b1);
    }
    float2 b2 = cmul(b1, b1);
    #pragma unroll
    for (int k = 0; k < 4; ++k){
        const int lo = k << 1, hi = lo + 1;
        float2 a = q[lo], b = q[hi];
        q[lo] = cadd(a, b);
        q[hi] = cmul(csub(a, b), b2);
    }
}
template<int SH0>
__device__ inline void dit_group8_o(float2 q[8], int r){
    const float c8 = 0.70710678118654752440f;
    const float2 R8 = make_float2(c8, -c8);
    float2 b2 = cis_m((float)(r << (SH0-2)));
    float2 b1 = cmul(b2, b2);
    float2 b0 = cmul(b1, b1);
    #pragma unroll
    for (int k = 0; k < 4; ++k){
        const int lo = k << 1, hi = lo + 1;
        float2 a = q[lo];
        float2 t2 = cmulc(q[hi], b0);
        q[lo] = cadd(a, t2);
        q[hi] = csub(a, t2);
    }
    float2 w1r = rot90(b1);
    #pragma unroll
    for (int k = 0; k < 4; ++k){
        const int jd = k & 1;
        const int lo = ((k & ~1) << 1) | jd, hi = lo + 2;
        float2 a = q[lo];
        float2 t2 = cmulc(q[hi], jd ? w1r : b1);
        q[lo] = cadd(a, t2);
        q[hi] = csub(a, t2);
    }
    float2 w2[4];
    w2[0] = b2; w2[1] = cmul(b2, R8); w2[2] = rot90(b2); w2[3] = rot90(w2[1]);
    #pragma unroll
    for (int k = 0; k < 4; ++k){
        const int lo = k, hi = k + 4;
        float2 a = q[lo];
        float2 t2 = cmulc(q[hi], w2[k]);
        q[lo] = cadd(a, t2);
        q[hi] = csub(a, t2);
    }
}

__device__ inline void lds_store8(float2* sc, const float2* q, int base, int S){
    #pragma unroll
    for (int l = 0; l < 8; ++l) sc[swz(base + S*l)] = q[l];
}
__device__ inline void lds_load8(const float2* sc, float2* q, int base, int S){
    #pragma unroll
    for (int l = 0; l < 8; ++l) q[l] = sc[swz(base + S*l)];
}

// forward rfft of one real row: M-pt complex FFT + Hermitian split. Barriers: 2.
__device__ void do_rfft(const float* __restrict__ srow, float2* __restrict__ dp,
                        float2* sc, int t){
    const float2* zp = (const float2*)srow;            // z[n] = row[2n] + i row[2n+1]
    float2 q[8];
    #pragma unroll
    for (int l = 0; l < 8; ++l) q[l] = zp[t + 512*l];
    dif_group8_o<1>(q, t);                             // S=512
    lds_store8(sc, q, t, 512);
    __syncthreads();
    {
        const int base = ((t>>6)<<9) | (t&63);
        lds_load8(sc, q, base, 64);
        dif_group8_o<4>(q, t&63);                      // S=64
        lds_store8(sc, q, base, 64);
    }
    {
        const int base = ((t>>3)<<6) | (t&7);
        lds_load8(sc, q, base, 8);
        dif_group8_o<7>(q, t&7);                       // S=8
        lds_store8(sc, q, base, 8);
    }
    {
        const int base = t << 3;
        lds_load8(sc, q, base, 1);
        dif_group8_o<10>(q, 0);                        // S=1
        lds_store8(sc, q, base, 1);
    }
    __syncthreads();
    #pragma unroll
    for (int l = 0; l < 8; ++l){
        const int j  = t + 512*l;
        const int k  = brev12(j);
        const int j2 = brev12((M - k) & (M-1));
        float2 Z  = sc[swz(j)];
        float2 Zm = sc[swz(j2)];
        float2 E = make_float2(0.5f*(Z.x + Zm.x), 0.5f*(Z.y - Zm.y));
        float2 D = make_float2(Z.x - Zm.x, Z.y + Zm.y);
        float2 O = make_float2(0.5f*D.y, -0.5f*D.x);
        float2 wk = cis_m((float)k);
        dp[j] = cadd(E, cmul(wk, O));
        if (j == 0) dp[M] = make_float2(Z.x - Z.y, 0.0f);
    }
}

// inverse: half-spectrum -> real row, *1/M + bias fused. Barriers: 3.
__device__ void do_irfft(const float2* __restrict__ yp, float* __restrict__ op,
                         float bv, float2* sc, int t){
    #pragma unroll
    for (int l = 0; l < 8; ++l){
        const int j = t + 512*l;
        sc[swz(j)] = yp[j];
    }
    float2 yM = yp[M];
    __syncthreads();
    #pragma unroll
    for (int l = 0; l < 4; ++l){
        const int j = (t + 512*l) << 1;                // even j -> k < 2048
        const int k = brev12(j);
        float2 Ym; int j2 = 0;
        if (k == 0){ Ym = yM; }
        else { j2 = brev12(M - k); Ym = sc[swz(j2)]; }
        float2 Y = sc[swz(j)];
        float2 E = make_float2(0.5f*(Y.x + Ym.x), 0.5f*(Y.y - Ym.y));
        float2 D = make_float2(0.5f*(Y.x - Ym.x), 0.5f*(Y.y + Ym.y));
        float2 wk = cis_m((float)k);
        float2 O = cmulc(D, wk);
        sc[swz(j)] = make_float2(E.x - O.y, E.y + O.x);
        if (k != 0){
            sc[swz(j2)] = make_float2(E.x + O.y, O.x - E.y);
        }
    }
    if (t == 0){   // j=1 <-> k=2048 self-paired; w_2048 = (0,-1)
        float2 Y = sc[swz(1)];
        float2 E = make_float2(Y.x, 0.0f);
        float2 D = make_float2(0.0f, Y.y);
        float2 O = make_float2(-D.y, D.x);
        sc[swz(1)] = make_float2(E.x - O.y, E.y + O.x);
    }
    __syncthreads();
    float2 q[8];
    {
        const int base = t << 3;
        lds_load8(sc, q, base, 1);
        dit_group8_o<12>(q, 0);                        // S=1
        lds_store8(sc, q, base, 1);
    }
    {
        const int base = ((t>>3)<<6) | (t&7);
        lds_load8(sc, q, base, 8);
        dit_group8_o<9>(q, t&7);                       // S=8
        lds_store8(sc, q, base, 8);
    }
    {
        const int base = ((t>>6)<<9) | (t&63);
        lds_load8(sc, q, base, 64);
        dit_group8_o<6>(q, t&63);                      // S=64
        lds_store8(sc, q, base, 64);
    }
    __syncthreads();
    lds_load8(sc, q, t, 512);
    dit_group8_o<3>(q, t);                             // S=512, fused to output
    const float scv = 1.0f/(float)M;
    float2* o2p = (float2*)op;
    #pragma unroll
    for (int l = 0; l < 8; ++l)
        o2p[t + 512*l] = make_float2(q[l].x*scv + bv, q[l].y*scv + bv);
}

// ---- THE mega-kernel: mlp -> rfft(320) -> filt(1026 tiles) -> irfft(256)
__global__ __launch_bounds__(NT) void mega(
        const float* __restrict__ x,  const float* __restrict__ w1,
        const float* __restrict__ b1, const float* __restrict__ w2,
        const float* __restrict__ b2, const float* __restrict__ w3,
        const float* __restrict__ b3, const float* __restrict__ bias,
        float* __restrict__ out, float2* __restrict__ Xh, float2* __restrict__ Yh,
        float2* __restrict__ Hh, float* __restrict__ H, unsigned* __restrict__ bar){
    __shared__ __align__(16) char smem[52480];
    const int t = threadIdx.x;
    const int blk = blockIdx.x;

    // ---- phase 1: MLP hidden state (32 positions per block) ----
    {
        float* sw1 = (float*)smem;        // 64
        float* sb1 = sw1 + 64;
        float* sb2 = sb1 + 64;
        float* sw2 = sb2 + 64;            // 4096
        float* h1s = sw2 + 4096;          // [32][65]
        for (int i = t; i < 64; i += NT){ sw1[i]=w1[i]; sb1[i]=b1[i]; sb2[i]=b2[i]; }
        for (int i = t; i < 4096; i += NT) sw2[i]=w2[i];
        __syncthreads();
        const int t0 = blk * 32;
        for (int e = t; e < 2048; e += NT){
            const int tl = e & 31, h = e >> 5;
            const float pos = (float)(t0 + tl) / (float)(T-1);
            h1s[tl*65 + h] = gelu_exact(pos*sw1[h] + sb1[h]);
        }
        __syncthreads();
        const int tl = t & 31, hg = t >> 5;            // hg 0..15
        float acc[4];
        #pragma unroll
        for (int u = 0; u < 4; ++u) acc[u] = sb2[hg*4 + u];
        for (int k = 0; k < HID; ++k){
            const float hv = h1s[tl*65 + k];
            const float4 w4 = *(const float4*)&sw2[k*HID + hg*4];
            acc[0] += hv*w4.x; acc[1] += hv*w4.y; acc[2] += hv*w4.z; acc[3] += hv*w4.w;
        }
        #pragma unroll
        for (int u = 0; u < 4; ++u)
            H[(size_t)(hg*4 + u)*T + t0 + tl] = gelu_exact(acc[u]);
    }
    grid_sync(bar);

    // ---- phase 2: 320 forward rffts (blocks 0..63 take a second signal) ----
    {
        float2* sc = (float2*)smem;
        do_rfft(x + (size_t)blk*T, Xh + (size_t)blk*JS, sc, t);
        if (blk < HID){
            __syncthreads();
            do_rfft(H + (size_t)blk*T, Hh + (size_t)blk*JS, sc, t);
        }
    }
    grid_sync(bar);

    // ---- phase 3: fused filter GEMM + contraction, 1026 tiles ----
    {
        float2* Xs  = (float2*)smem;      // [32][73]
        float2* Flt = Xs + 32*73;         // [16][8][33]
        for (int tile = blk; tile < 1026; tile += NB){
            __syncthreads();
            const int oh = tile & 1;
            const int f0 = (tile >> 1) * 8;
            if (t < 256){                 // stage X tile: row t, 64B segment
                const float4* xp4 = (const float4*)(Xh + (size_t)t*JS + f0);
                float4 u0 = xp4[0], u1 = xp4[1], u2 = xp4[2], u3 = xp4[3];
                const int b = t >> 5, i = t & 31;
                Xs[i*73 + 0*9 + b] = make_float2(u0.x,u0.y);
                Xs[i*73 + 1*9 + b] = make_float2(u0.z,u0.w);
                Xs[i*73 + 2*9 + b] = make_float2(u1.x,u1.y);
                Xs[i*73 + 3*9 + b] = make_float2(u1.z,u1.w);
                Xs[i*73 + 4*9 + b] = make_float2(u2.x,u2.y);
                Xs[i*73 + 5*9 + b] = make_float2(u2.z,u2.w);
                Xs[i*73 + 6*9 + b] = make_float2(u3.x,u3.y);
                Xs[i*73 + 7*9 + b] = make_float2(u3.z,u3.w);
            }
            // phase A: 1 oi per thread, 8 f-cols
            const int oiG = oh*512 + t;
            float2 acc[8];
            #pragma unroll
            for (int f = 0; f < 8; ++f) acc[f] = make_float2(0.f, 0.f);
            #pragma unroll 4
            for (int h = 0; h < HID; ++h){
                const float wv = w3[(size_t)h*(CIN*COUT) + oiG];           // coalesced
                const float4* hp4 = (const float4*)(Hh + (size_t)h*JS + f0); // uniform 64B
                float4 a0 = hp4[0], a1 = hp4[1], a2 = hp4[2], a3 = hp4[3];
                const float hr[8] = {a0.x,a0.z,a1.x,a1.z,a2.x,a2.z,a3.x,a3.z};
                const float hi[8] = {a0.y,a0.w,a1.y,a1.w,a2.y,a2.w,a3.y,a3.w};
                #pragma unroll
                for (int f = 0; f < 8; ++f){
                    acc[f].x += wv*hr[f];
                    acc[f].y += wv*hi[f];
                }
            }
            if (f0 == 0) acc[0].x += (float)T * b3[oiG];
            {
                const int oL = t >> 5, ii = t & 31;
                #pragma unroll
                for (int f = 0; f < 8; ++f)
                    Flt[(oL*8 + f)*33 + ii] = acc[f];
            }
            __syncthreads();
            // phase B: o2 = t>>5 (16), f2 = (t>>2)&7, g = t&3; batches b = 4j+g
            const int o2 = t >> 5, f2 = (t >> 2) & 7, g = t & 3;
            float2 y[2];
            y[0] = make_float2(0.f, 0.f); y[1] = make_float2(0.f, 0.f);
            #pragma unroll 8
            for (int i0 = 0; i0 < CIN; ++i0){
                const float2 fv = Flt[(o2*8 + f2)*33 + i0];
                #pragma unroll
                for (int j = 0; j < 2; ++j){
                    const float2 xv = Xs[i0*73 + f2*9 + (4*j + g)];
                    y[j].x += xv.x*fv.x - xv.y*fv.y;
                    y[j].y += xv.x*fv.y + xv.y*fv.x;
                }
            }
            if (f0 + f2 <= M){
                const int o = oh*16 + o2;
                #pragma unroll
                for (int j = 0; j < 2; ++j){
                    const int b = 4*j + g;
                    Yh[((size_t)(b*COUT + o))*JS + f0 + f2] = y[j];
                }
            }
        }
    }
    grid_sync(bar);

    // ---- phase 4: 256 inverse rffts + bias ----
    {
        float2* sc = (float2*)smem;
        do_irfft(Yh + (size_t)blk*JS, out + (size_t)blk*T, bias[blk & (COUT-1)], sc, t);
    }
}

extern "C" void kernel_launch(void* const* d_in, const int* in_sizes, int n_in,
                              void* d_out, int out_size, void* d_ws, size_t ws_size,
                              hipStream_t stream){
    const float* x    = (const float*)d_in[0];
    const float* w1   = (const float*)d_in[1];
    const float* b1   = (const float*)d_in[2];
    const float* w2   = (const float*)d_in[3];
    const float* b2   = (const float*)d_in[4];
    const float* w3   = (const float*)d_in[5];
    const float* b3   = (const float*)d_in[6];
    const float* bias = (const float*)d_in[7];
    float* out = (float*)d_out;

    // Workspace: Xh@0 (8.4M) | Yh@9M (8.4M) | Hh@18M (2.1M) | H@21M (2M) | bar@23M
    char* ws = (char*)d_ws;
    float2*  Xh  = (float2*)ws;
    float2*  Yh  = (float2*)(ws + (size_t)9*1024*1024);
    float2*  Hh  = (float2*)(ws + (size_t)18*1024*1024);
    float*   H   = (float*) (ws + (size_t)21*1024*1024);
    unsigned* bar= (unsigned*)(ws + (size_t)23*1024*1024);

    hipMemsetAsync(bar, 0, 64, stream);    // zero the grid-barrier counter (capture-legal)
    hipLaunchKernelGGL(mega, dim3(NB), dim3(NT), 0, stream,
                       x, w1, b1, w2, b2, w3, b3, bias, out, Xh, Yh, Hh, H, bar);
}

// Round 13
// 129.012 us; speedup vs baseline: 3.3610x; 3.3610x over previous
//
#include <hip/hip_runtime.h>
#include <math.h>

#define T 8192
#define M 4096          // half length (complex FFT size)
#define JS 4104         // padded row stride (elements) for half-spectra
#define B 8
#define CIN 32
#define COUT 32
#define HID 64
#define FT8 8

__device__ inline float2 cadd(float2 a, float2 b){ return make_float2(a.x+b.x, a.y+b.y); }
__device__ inline float2 csub(float2 a, float2 b){ return make_float2(a.x-b.x, a.y-b.y); }
__device__ inline float2 cmul(float2 a, float2 b){ return make_float2(a.x*b.x - a.y*b.y, a.x*b.y + a.y*b.x); }
__device__ inline float2 cmulc(float2 a, float2 b){ // a * conj(b)
    return make_float2(a.x*b.x + a.y*b.y, a.y*b.x - a.x*b.y); }
__device__ inline float2 rot90(float2 a){ return make_float2(a.y, -a.x); }   // * (0,-1)
__device__ inline int swz(int p){ return p ^ ((p >> 5) & 31); }
__device__ inline int brev12(int v){ return (int)(__brev((unsigned)v) >> 20); }

// e^{-2*pi*i * k/8192} computed on the fly (hw v_sin/v_cos; ~2e-7 error)
__device__ inline float2 cis_m(float k){
    const float w = -7.669903939428206e-4f;    // -2*pi/8192
    float a = w * k;
    return make_float2(__cosf(a), __sinf(a));
}

__device__ inline float gelu_exact(float x){
    return 0.5f*x*(1.0f + erff(x*0.70710678118654752440f));
}

// ---- register-blocked radix-2 groups, 8 pts/thread, on-the-fly twiddles.
// S<<SH0 == 1024 in every instantiation -> stage deltas are -1/8 and -1/4 turns;
// stage bases are b, b^2, b^4 of one angle -> 1 sincos + 2 squarings per group.
template<int SH0>
__device__ inline void dif_group8_o(float2 q[8], int r){
    const float c8 = 0.70710678118654752440f;
    const float2 R8 = make_float2(c8, -c8);            // cis(-1/8 turn)
    float2 b0 = cis_m((float)(r << SH0));              // stage-0 base
    float2 w0[4];
    w0[0] = b0; w0[1] = cmul(b0, R8); w0[2] = rot90(b0); w0[3] = rot90(w0[1]);
    #pragma unroll
    for (int k = 0; k < 4; ++k){
        const int lo = k, hi = k + 4;
        float2 a = q[lo], b = q[hi];
        q[lo] = cadd(a, b);
        q[hi] = cmul(csub(a, b), w0[k]);
    }
    float2 b1 = cmul(b0, b0);
    float2 w1r = rot90(b1);
    #pragma unroll
    for (int k = 0; k < 4; ++k){
        const int jd = k & 1;
        const int lo = ((k & ~1) << 1) | jd, hi = lo + 2;
        float2 a = q[lo], b = q[hi];
        q[lo] = cadd(a, b);
        q[hi] = cmul(csub(a, b), jd ? w1r : b1);
    }
    float2 b2 = cmul(b1, b1);
    #pragma unroll
    for (int k = 0; k < 4; ++k){
        const int lo = k << 1, hi = lo + 1;
        float2 a = q[lo], b = q[hi];
        q[lo] = cadd(a, b);
        q[hi] = cmul(csub(a, b), b2);
    }
}
template<int SH0>
__device__ inline void dit_group8_o(float2 q[8], int r){
    const float c8 = 0.70710678118654752440f;
    const float2 R8 = make_float2(c8, -c8);
    float2 b2 = cis_m((float)(r << (SH0-2)));          // finest base (stage 2)
    float2 b1 = cmul(b2, b2);
    float2 b0 = cmul(b1, b1);
    #pragma unroll
    for (int k = 0; k < 4; ++k){
        const int lo = k << 1, hi = lo + 1;
        float2 a = q[lo];
        float2 t2 = cmulc(q[hi], b0);
        q[lo] = cadd(a, t2);
        q[hi] = csub(a, t2);
    }
    float2 w1r = rot90(b1);
    #pragma unroll
    for (int k = 0; k < 4; ++k){
        const int jd = k & 1;
        const int lo = ((k & ~1) << 1) | jd, hi = lo + 2;
        float2 a = q[lo];
        float2 t2 = cmulc(q[hi], jd ? w1r : b1);
        q[lo] = cadd(a, t2);
        q[hi] = csub(a, t2);
    }
    float2 w2[4];
    w2[0] = b2; w2[1] = cmul(b2, R8); w2[2] = rot90(b2); w2[3] = rot90(w2[1]);
    #pragma unroll
    for (int k = 0; k < 4; ++k){
        const int lo = k, hi = k + 4;
        float2 a = q[lo];
        float2 t2 = cmulc(q[hi], w2[k]);
        q[lo] = cadd(a, t2);
        q[hi] = csub(a, t2);
    }
}

// AoS float2 LDS + swz: b64 DS ops
__device__ inline void lds_store8(float2* sc, const float2* q, int base, int S){
    #pragma unroll
    for (int l = 0; l < 8; ++l) sc[swz(base + S*l)] = q[l];
}
__device__ inline void lds_load8(const float2* sc, float2* q, int base, int S){
    #pragma unroll
    for (int l = 0; l < 8; ++l) q[l] = sc[swz(base + S*l)];
}

// rfft of a real row (length T) via M-point complex FFT + Hermitian split.
// Merged launch: sig<256 -> x rows -> Xh; sig>=256 -> H rows -> Hh. Barriers: 2.
// __launch_bounds__(512,4): cap VGPR<=128 -> 2 blocks/CU so doubled-up CUs overlap.
__global__ __launch_bounds__(512, 4) void rfft_all(const float* __restrict__ x,
        const float* __restrict__ H, float2* __restrict__ Xh, float2* __restrict__ Hh){
    __shared__ float2 sc[M];
    const int t = threadIdx.x;
    const int sig = blockIdx.x;
    const float* srow;
    float2* dp;
    if (sig < B*CIN){ srow = x + (size_t)sig*T;        dp = Xh + (size_t)sig*JS; }
    else            { srow = H + (size_t)(sig-B*CIN)*T; dp = Hh + (size_t)(sig-B*CIN)*JS; }
    const float2* zp = (const float2*)srow;            // z[n] = x[2n] + i x[2n+1]
    float2 q[8];
    #pragma unroll
    for (int l = 0; l < 8; ++l) q[l] = zp[t + 512*l];
    dif_group8_o<1>(q, t);                             // S=512 group
    lds_store8(sc, q, t, 512);
    __syncthreads();                                   // cross-wave regroup
    {
        const int base = ((t>>6)<<9) | (t&63);         // 512-pt chunk of wave t>>6
        lds_load8(sc, q, base, 64);
        dif_group8_o<4>(q, t&63);                      // S=64
        lds_store8(sc, q, base, 64);
    }
    {
        const int base = ((t>>3)<<6) | (t&7);
        lds_load8(sc, q, base, 8);
        dif_group8_o<7>(q, t&7);                       // S=8
        lds_store8(sc, q, base, 8);
    }
    {
        const int base = t << 3;
        lds_load8(sc, q, base, 1);
        dif_group8_o<10>(q, 0);                        // S=1
        lds_store8(sc, q, base, 1);
    }
    __syncthreads();                                   // split reads cross-chunk pairs
    // Hermitian split: X[k] = E + w_k*O; Zm = Z[M-k]
    #pragma unroll
    for (int l = 0; l < 8; ++l){
        const int j  = t + 512*l;
        const int k  = brev12(j);
        const int j2 = brev12((M - k) & (M-1));
        float2 Z  = sc[swz(j)];
        float2 Zm = sc[swz(j2)];
        float2 E = make_float2(0.5f*(Z.x + Zm.x), 0.5f*(Z.y - Zm.y));
        float2 D = make_float2(Z.x - Zm.x, Z.y + Zm.y);        // Z - conj(Zm)
        float2 O = make_float2(0.5f*D.y, -0.5f*D.x);           // -i/2 * D
        float2 wk = cis_m((float)k);
        dp[j] = cadd(E, cmul(wk, O));
        if (j == 0) dp[M] = make_float2(Z.x - Z.y, 0.0f);      // X[M] = ReZ0 - ImZ0
    }
}

// irfft: half-spectrum (packed layout) -> real row, *1/M + bias fused. Barriers: 3.
__global__ __launch_bounds__(512, 4) void irfft_out(const float2* __restrict__ Yh,
        const float* __restrict__ bias, float* __restrict__ out){
    __shared__ float2 sc[M];
    const int t = threadIdx.x;
    const int sig = blockIdx.x;
    const float2* yp = Yh + (size_t)sig*JS;
    #pragma unroll
    for (int l = 0; l < 8; ++l){
        const int j = t + 512*l;
        sc[swz(j)] = yp[j];
    }
    float2 yM = yp[M];
    __syncthreads();
    // Hermitian combine, even-j owners only (k = brev12(j) < 2048):
    #pragma unroll
    for (int l = 0; l < 4; ++l){
        const int j = (t + 512*l) << 1;                        // even j
        const int k = brev12(j);                               // k < 2048
        float2 Ym; int j2 = 0;
        if (k == 0){ Ym = yM; }
        else { j2 = brev12(M - k); Ym = sc[swz(j2)]; }
        float2 Y = sc[swz(j)];
        float2 E = make_float2(0.5f*(Y.x + Ym.x), 0.5f*(Y.y - Ym.y));
        float2 D = make_float2(0.5f*(Y.x - Ym.x), 0.5f*(Y.y + Ym.y));   // (Y - conj(Ym))/2
        float2 wk = cis_m((float)k);
        float2 O = cmulc(D, wk);
        sc[swz(j)] = make_float2(E.x - O.y, E.y + O.x);                 // Z[k]
        if (k != 0){
            sc[swz(j2)] = make_float2(E.x + O.y, O.x - E.y);            // Z[M-k]
        }
    }
    if (t == 0){   // j=1 <-> k=2048 self-paired; w_2048 = (0,-1): O = (-D.y, D.x)
        float2 Y = sc[swz(1)];
        float2 E = make_float2(Y.x, 0.0f);
        float2 D = make_float2(0.0f, Y.y);
        float2 O = make_float2(-D.y, D.x);
        sc[swz(1)] = make_float2(E.x - O.y, E.y + O.x);
    }
    __syncthreads();
    float2 q[8];
    {
        const int base = t << 3;
        lds_load8(sc, q, base, 1);
        dit_group8_o<12>(q, 0);                        // S=1
        lds_store8(sc, q, base, 1);
    }
    {
        const int base = ((t>>3)<<6) | (t&7);
        lds_load8(sc, q, base, 8);
        dit_group8_o<9>(q, t&7);                       // S=8
        lds_store8(sc, q, base, 8);
    }
    {
        const int base = ((t>>6)<<9) | (t&63);
        lds_load8(sc, q, base, 64);
        dit_group8_o<6>(q, t&63);                      // S=64
        lds_store8(sc, q, base, 64);
    }
    __syncthreads();                                   // S=512 group reads cross-wave
    lds_load8(sc, q, t, 512);
    dit_group8_o<3>(q, t);                             // final group fused to output
    const float scv = 1.0f/(float)M;
    const float bv = bias[sig & (COUT-1)];
    float2* op = (float2*)(out + (size_t)sig*T);
    #pragma unroll
    for (int l = 0; l < 8; ++l)
        op[t + 512*l] = make_float2(q[l].x*scv + bv, q[l].y*scv + bv);
}

// MLP hidden state H[h*T + t].
#define TB 32
__global__ __launch_bounds__(256) void mlp_hidden(const float* __restrict__ w1, const float* __restrict__ b1,
                           const float* __restrict__ w2, const float* __restrict__ b2,
                           float* __restrict__ H){
    __shared__ float sw1[HID], sb1[HID], sw2[HID*HID], sb2[HID];
    __shared__ float h1s[TB][HID+1];
    const int tid = threadIdx.x;
    for (int i = tid; i < HID; i += 256){ sw1[i]=w1[i]; sb1[i]=b1[i]; sb2[i]=b2[i]; }
    for (int i = tid; i < HID*HID; i += 256) sw2[i]=w2[i];
    __syncthreads();
    const int t0 = blockIdx.x * TB;
    for (int e = tid; e < TB*HID; e += 256){
        const int tl = e & (TB-1), h = e >> 5;
        const float pos = (float)(t0 + tl) / (float)(T-1);
        h1s[tl][h] = gelu_exact(pos*sw1[h] + sb1[h]);
    }
    __syncthreads();
    const int tl = tid & (TB-1), hg = tid >> 5;   // hg 0..7
    float acc[8];
    #pragma unroll
    for (int u = 0; u < 8; ++u) acc[u] = sb2[hg*8 + u];
    for (int k = 0; k < HID; ++k){
        const float hv = h1s[tl][k];
        const float4 wa = *(const float4*)&sw2[k*HID + hg*8];
        const float4 wb = *(const float4*)&sw2[k*HID + hg*8 + 4];
        acc[0] += hv*wa.x; acc[1] += hv*wa.y; acc[2] += hv*wa.z; acc[3] += hv*wa.w;
        acc[4] += hv*wb.x; acc[5] += hv*wb.y; acc[6] += hv*wb.z; acc[7] += hv*wb.w;
    }
    #pragma unroll
    for (int u = 0; u < 8; ++u)
        H[(size_t)(hg*8 + u)*T + t0 + tl] = gelu_exact(acc[u]);
}

// Fused filter-spectrum GEMM + channel contraction over packed half-spectra.
// FT=8: 64B gather granule. grid = (2, 513): oh fast -> paired Xh reads temporally adjacent.
__global__ __launch_bounds__(256) void filt_contract(const float* __restrict__ w3,
        const float* __restrict__ b3, const float2* __restrict__ Hh,
        const float2* __restrict__ Xh, float2* __restrict__ Yh){
    __shared__ float2 Xs[CIN][73];          // [i][f*9 + b]
    __shared__ float2 Flt[16][FT8][33];     // [oL][f][i]
    const int t = threadIdx.x;
    const int f0 = blockIdx.y * FT8;
    const int oh = blockIdx.x;              // o-half: o in [oh*16, oh*16+16)
    // stage X tile: row t, 64B contiguous segment (4x float4)
    {
        const float4* xp4 = (const float4*)(Xh + (size_t)t*JS + f0);
        float4 u0 = xp4[0], u1 = xp4[1], u2 = xp4[2], u3 = xp4[3];
        const int b = t >> 5, i = t & 31;
        Xs[i][0*9+b] = make_float2(u0.x,u0.y); Xs[i][1*9+b] = make_float2(u0.z,u0.w);
        Xs[i][2*9+b] = make_float2(u1.x,u1.y); Xs[i][3*9+b] = make_float2(u1.z,u1.w);
        Xs[i][4*9+b] = make_float2(u2.x,u2.y); Xs[i][5*9+b] = make_float2(u2.z,u2.w);
        Xs[i][6*9+b] = make_float2(u3.x,u3.y); Xs[i][7*9+b] = make_float2(u3.z,u3.w);
    }
    // phase A: 2 oi per thread (oiG = oh*512 + 2t, 2t+1), 8 f-cols
    const int oiG = oh*512 + (t << 1);
    float2 acc[2][FT8];
    #pragma unroll
    for (int ii = 0; ii < 2; ++ii)
        #pragma unroll
        for (int f = 0; f < FT8; ++f) acc[ii][f] = make_float2(0.f, 0.f);
    #pragma unroll 4
    for (int h = 0; h < HID; ++h){
        const float2 w2v = *(const float2*)(w3 + (size_t)h*(CIN*COUT) + oiG);  // coalesced
        const float4* hp4 = (const float4*)(Hh + (size_t)h*JS + f0);           // block-uniform 64B
        float4 a0 = hp4[0], a1 = hp4[1], a2 = hp4[2], a3 = hp4[3];
        const float hr[8] = {a0.x,a0.z,a1.x,a1.z,a2.x,a2.z,a3.x,a3.z};
        const float hi[8] = {a0.y,a0.w,a1.y,a1.w,a2.y,a2.w,a3.y,a3.w};
        const float wv[2] = {w2v.x, w2v.y};
        #pragma unroll
        for (int ii = 0; ii < 2; ++ii)
            #pragma unroll
            for (int f = 0; f < FT8; ++f){
                acc[ii][f].x += wv[ii]*hr[f];
                acc[ii][f].y += wv[ii]*hi[f];
            }
    }
    if (f0 == 0){   // DC: filter spectrum += T*b3
        #pragma unroll
        for (int ii = 0; ii < 2; ++ii)
            acc[ii][0].x += (float)T * b3[oiG + ii];
    }
    {
        const int oL = t >> 4;
        const int ib = (t & 15) << 1;
        #pragma unroll
        for (int ii = 0; ii < 2; ++ii)
            #pragma unroll
            for (int f = 0; f < FT8; ++f)
                Flt[oL][f][ib + ii] = acc[ii][f];
    }
    __syncthreads();
    // phase B: thread = (o2 = t>>4, f2 = (t>>1)&7, g = t&1); batches b = 4g+j
    const int o2 = t >> 4, f2 = (t >> 1) & 7, g = t & 1;
    float2 y[4];
    #pragma unroll
    for (int j = 0; j < 4; ++j) y[j] = make_float2(0.f, 0.f);
    #pragma unroll 8
    for (int i0 = 0; i0 < CIN; ++i0){
        const float2 fv = Flt[o2][f2][i0];
        #pragma unroll
        for (int j = 0; j < 4; ++j){
            const float2 xv = Xs[i0][f2*9 + ((g << 2) | j)];
            y[j].x += xv.x*fv.x - xv.y*fv.y;
            y[j].y += xv.x*fv.y + xv.y*fv.x;
        }
    }
    if (f0 + f2 <= M){
        #pragma unroll
        for (int j = 0; j < 4; ++j){
            const int b = (g << 2) | j;
            const int o = oh*16 + o2;
            Yh[((size_t)(b*COUT + o))*JS + f0 + f2] = y[j];
        }
    }
}

extern "C" void kernel_launch(void* const* d_in, const int* in_sizes, int n_in,
                              void* d_out, int out_size, void* d_ws, size_t ws_size,
                              hipStream_t stream){
    const float* x    = (const float*)d_in[0];
    const float* w1   = (const float*)d_in[1];
    const float* b1   = (const float*)d_in[2];
    const float* w2   = (const float*)d_in[3];
    const float* b2   = (const float*)d_in[4];
    const float* w3   = (const float*)d_in[5];
    const float* b3   = (const float*)d_in[6];
    const float* bias = (const float*)d_in[7];
    float* out = (float*)d_out;

    // Workspace: Xh 8.5MB | Yh 8.5MB | Hh 2.2MB | H 2MB  (~23 MB)
    char* ws = (char*)d_ws;
    float2* Xh = (float2*)ws;
    float2* Yh = (float2*)(ws + (size_t)9*1024*1024);
    float2* Hh = (float2*)(ws + (size_t)18*1024*1024);
    float*  H  = (float*) (ws + (size_t)21*1024*1024);

    hipLaunchKernelGGL(mlp_hidden,    dim3(T/TB),         dim3(256), 0, stream, w1, b1, w2, b2, H);
    hipLaunchKernelGGL(rfft_all,      dim3(B*CIN+HID),    dim3(512), 0, stream, x, H, Xh, Hh);
    hipLaunchKernelGGL(filt_contract, dim3(2, M/FT8 + 1), dim3(256), 0, stream, w3, b3, Hh, Xh, Yh);
    hipLaunchKernelGGL(irfft_out,     dim3(B*COUT),       dim3(512), 0, stream, Yh, bias, out);
}